// Round 5
// baseline (131.032 us; speedup 1.0000x reference)
//
#include <hip/hip_runtime.h>
#include <cmath>

#define D 128
#define BM 128   // A rows per block tile (held in registers)
#define BN 64    // B cols per half-tile step
#define NSEG 12  // segments per strip-pair -> 64*12 = 768 blocks = 3/CU exactly
#define LOG2E 1.4426950408889634

typedef __attribute__((ext_vector_type(8))) _Float16 f16x8;
typedef __attribute__((ext_vector_type(4))) float f32x4;
typedef __attribute__((ext_vector_type(2))) float f32x2;

// ---------------------------------------------------------------------------
// Prep: fp32 x -> fp16 (RTN) combined [x1; x2], per-row El[r] =
// -gamma*log2e*|row|^2 (log2-domain), AND zero the 64 acc slots (block 0).
// ---------------------------------------------------------------------------
__global__ __launch_bounds__(256) void prep_kernel(
    const float* __restrict__ x1, const float* __restrict__ x2,
    _Float16* __restrict__ xh, float* __restrict__ El,
    double* __restrict__ acc, float gl, int N) {
    int tid = threadIdx.x;
    if (blockIdx.x == 0 && tid < 64) acc[tid] = 0.0;
    int r = blockIdx.x * 16 + (tid >> 4);
    if (r >= 2 * N) return;
    int l = tid & 15;
    const float* row = (r < N) ? x1 + (size_t)r * D : x2 + (size_t)(r - N) * D;
    float4 v0 = ((const float4*)row)[l * 2];
    float4 v1 = ((const float4*)row)[l * 2 + 1];
    float v[8] = {v0.x, v0.y, v0.z, v0.w, v1.x, v1.y, v1.z, v1.w};
    float p = 0.f;
    _Float16 h8[8];
#pragma unroll
    for (int j = 0; j < 8; ++j) {
        p = fmaf(v[j], v[j], p);
        h8[j] = (_Float16)v[j];   // RTN-even
    }
    *(uint4*)(xh + (size_t)r * D + l * 8) = *(uint4*)h8;
#pragma unroll
    for (int off = 8; off; off >>= 1) p += __shfl_down(p, off, 16);
    if (l == 0) El[r] = gl * p;   // gl = -gamma*log2e
}

// ---------------------------------------------------------------------------
// R15. Post-mortem chain:
//   R0/R12/R14: three different schedules ALL at 50-52us, MfmaUtil pinned
//   at 26%. Per-CU cycle audit: MFMA ~40k + exp2/VALU ~43k + ds_read ~25k
//   + staging ~15k SUMS to the measured 125k cy -- pipes run SERIALLY.
//   Cause: the two s_barriers per half-tile phase-lock all waves (everyone
//   MFMAs together, then everyone exp2s together); cross-wave pipe overlap
//   (m114) never happens. Occupancy axis falsified (R14: +50% waves, 0 gain).
// R15 removes the phase-lock entirely:
//   * NO LDS tile, NO barriers, NO staging DMA, NO manual vmcnt in the loop.
//     B fragments are loaded straight from global into regs -- xh is 4MB and
//     L2-resident per XCD (B replication = 528MB total ~= 15-18 TB/s << 34.5
//     TB/s L2 ceiling). Compiler emits its own counted vmcnt waits; with no
//     barrier there is no forced drain anywhere.
//   * Waves free-run -> natural phase skew -> MFMA/trans/VALU/VMEM overlap
//     across the 12 resident waves/CU.
//   * LDS = 4 doubles (final reduction only). Bank conflicts -> ~0.
//   * Same iteration geometry as R14: strip-pair p paired with 127-p,
//     NSEG=12 segments, half-tiles of 128 rows x 64 cols; wave owns 64x32.
//   * Register budget (256,3)=170: a 64 + C 32 (AGPR, unified file) +
//     hoisted b <=32 + ea4 16 + misc ~= 165. Tripwire: WRITE_SIZE KB-scale.
// Signed weight: bi==bj: +1; same class off-diag: +2; cross class: -2.
// MFMA: v_mfma_f32_16x16x32_f16 (m89/m91-HW-verified C/D layout).
// ---------------------------------------------------------------------------
__global__ __launch_bounds__(256, 3) void mmd_mfma_kernel(
    const _Float16* __restrict__ xh, const float* __restrict__ El,
    double* __restrict__ acc, float c2l, int N) {
    __shared__ double red[4];   // reduction scratch only -- no tile LDS

    int tid = threadIdx.x;
    int lane = tid & 63, wave = tid >> 6;      // 4 waves
    int quad = lane >> 4, l16 = lane & 15;
    int wrow = (wave & 1) * 64;                // 2 row-groups of 64
    int wcol = (wave >> 1) * 32;               // 2 col-groups of 32

    int nt2 = 2 * N / BM;        // 128 combined block-rows
    int half = N / BM;           // first `half` are x1
    int p = blockIdx.x / NSEG;   // strip pair: rows p and nt2-1-p
    int s = blockIdx.x % NSEG;
    int tpp = nt2 + 1;           // tiles per pair (129)
    int q = tpp / NSEG, r = tpp % NSEG;
    int t0 = s * q + (s < r ? s : r);
    int nt = q + (s < r ? 1 : 0);    // 10 or 11 tiles
    int H = 2 * nt;                  // half-tiles (BN=64 cols each)

    auto BI = [&](int tt) { return tt <= p ? p : nt2 - 1 - p; };
    auto BJ = [&](int tt) { return tt <= p ? tt : tt - p - 1; };

    f16x8 a[4][4];       // A fragments: rows wrow..+64, full K=128 (64 VGPR)
    float4 ea4[4];       // A-side El (reloaded only on strip-row change)
    int curA = -1;
    double dsum = 0.0;

    for (int ht = 0; ht < H; ++ht) {
        int tt = t0 + (ht >> 1), h = ht & 1;
        int bi = BI(tt), bj = BJ(tt);
        int aBase = bi * BM;
        int bcolBase = bj * BM + h * BN;
        float w = (bi == bj) ? 1.0f : 2.0f;
        if ((bi < half) != (bj < half)) w = -2.0f;

        // A reload only when the strip row changes (<= 2x per block).
        if (aBase != curA) {
            curA = aBase;
#pragma unroll
            for (int u = 0; u < 4; ++u) {
                int ar = aBase + wrow + u * 16 + l16;
#pragma unroll
                for (int j = 0; j < 4; ++j) {
                    int g = (j >> 1) * 8 + (j & 1) * 4 + quad;
                    a[u][j] = *(const f16x8*)(xh + (size_t)ar * D + g * 8);
                }
            }
            int arow0 = aBase + wrow + quad * 4;
#pragma unroll
            for (int ti = 0; ti < 4; ++ti)
                ea4[ti] = *(const float4*)&El[arow0 + ti * 16];
        }

        // B-side El for this half-tile (L2-hit; latency hides under MFMA).
        int bcol0 = bcolBase + wcol + l16;
        float ebv0 = El[bcol0];
        float ebv1 = El[bcol0 + 16];

        f32x4 C[4][2];
#pragma unroll
        for (int ti = 0; ti < 4; ++ti)
#pragma unroll
            for (int tj = 0; tj < 2; ++tj) C[ti][tj] = {0.f, 0.f, 0.f, 0.f};

        // MFMA phase: B fragments straight from global (L2). The 8 loads are
        // independent of each other and of the MFMAs of earlier j -- the
        // compiler hoists/pipelines them with fine-grained vmcnt waits.
#pragma unroll
        for (int j = 0; j < 4; ++j) {
            int gb = (j >> 1) * 8 + (j & 1) * 4 + quad;
            f16x8 b[2];
#pragma unroll
            for (int u = 0; u < 2; ++u) {
                int br = bcolBase + wcol + u * 16 + l16;
                b[u] = *(const f16x8*)(xh + (size_t)br * D + gb * 8);
            }
#pragma unroll
            for (int ti = 0; ti < 4; ++ti)
#pragma unroll
                for (int tj = 0; tj < 2; ++tj)
                    C[ti][tj] = __builtin_amdgcn_mfma_f32_16x16x32_f16(
                        a[ti][j], b[tj], C[ti][tj], 0, 0, 0);
        }

        // epilogue: entry = exp2(c2l*d + ea) * 2^eb; accumulate f64 in regs.
        // C/D layout (m89-verified): col = lane&15, row = quad*4 + reg.
        f32x2 cc = {c2l, c2l};
        float lsum = 0.f;
#pragma unroll
        for (int tj = 0; tj < 2; ++tj) {
            f32x2 p2 = {0.f, 0.f};
#pragma unroll
            for (int ti = 0; ti < 4; ++ti) {
                f32x4 d = C[ti][tj];
                f32x2 a01 = cc * f32x2{d.x, d.y} + f32x2{ea4[ti].x, ea4[ti].y};
                f32x2 a23 = cc * f32x2{d.z, d.w} + f32x2{ea4[ti].z, ea4[ti].w};
                f32x2 e, e2;
                e.x = __builtin_amdgcn_exp2f(a01.x);
                e.y = __builtin_amdgcn_exp2f(a01.y);
                e2.x = __builtin_amdgcn_exp2f(a23.x);
                e2.y = __builtin_amdgcn_exp2f(a23.y);
                p2 += e + e2;
            }
            lsum = fmaf(p2.x + p2.y,
                        __builtin_amdgcn_exp2f(tj ? ebv1 : ebv0), lsum);
        }
        dsum += (double)lsum * (double)w;
    }

    // block reduction (the ONLY synchronization in the kernel)
#pragma unroll
    for (int off = 32; off; off >>= 1) dsum += __shfl_down(dsum, off);
    if (lane == 0) red[wave] = dsum;
    __syncthreads();
    if (tid == 0)
        atomicAdd(&acc[blockIdx.x & 63], red[0] + red[1] + red[2] + red[3]);
}

// ---------------------------------------------------------------------------
// Finalize: out = sqrt(max(S/N^2, 0)), S already = S11 + S22 - 2*S12.
// ---------------------------------------------------------------------------
__global__ __launch_bounds__(64) void mmd_finalize_kernel(
    const double* __restrict__ acc, float* __restrict__ out, int N) {
    int l = threadIdx.x;
    double v = acc[l];
#pragma unroll
    for (int off = 32; off; off >>= 1) v += __shfl_down(v, off);
    if (l == 0) {
        double nn = (double)N * (double)N;
        double s = v / nn;
        out[0] = (float)sqrt(s > 0.0 ? s : 0.0);
    }
}

extern "C" void kernel_launch(void* const* d_in, const int* in_sizes, int n_in,
                              void* d_out, int out_size, void* d_ws, size_t ws_size,
                              hipStream_t stream) {
    const float* x1 = (const float*)d_in[0];
    const float* x2 = (const float*)d_in[1];
    int N = in_sizes[0] / D;  // 8192

    // ws layout: [0,512) acc (64 doubles); El @8192 (2N f32);
    // xh @73728 (2N*128 fp16 = 4 MB). Total ~4.07 MB.
    double* acc = (double*)d_ws;
    float* El = (float*)((char*)d_ws + 8192);
    _Float16* xh = (_Float16*)((char*)d_ws + 73728);

    double lg = lgamma(0.5 * (D + 1)) - lgamma(0.5 * D);
    double gz = 2.0 * exp(lg);
    double gamma = 1.0 / (2.0 * gz * gz);
    float gl = (float)(-gamma * LOG2E);        // El scale
    float c2l = (float)(2.0 * gamma * LOG2E);  // dot scale (log2 domain)

    prep_kernel<<<(2 * N + 15) / 16, 256, 0, stream>>>(x1, x2, xh, El, acc, gl, N);

    int nblocks = 64 * NSEG;   // 64 strip-pairs x 12 segments = 768 = 3/CU
    mmd_mfma_kernel<<<nblocks, 256, 0, stream>>>(xh, El, acc, c2l, N);

    mmd_finalize_kernel<<<1, 64, 0, stream>>>(acc, (float*)d_out, N);
}